// Round 2
// baseline (1070.914 us; speedup 1.0000x reference)
//
#include <hip/hip_runtime.h>
#include <hip/hip_bf16.h>
#include <math.h>

typedef __attribute__((ext_vector_type(8))) short bf16x8;
typedef __attribute__((ext_vector_type(4))) float f32x4;

#define NQ 16384
#define NN 32
#define FI 128
#define FO 256
#define KPN 15
#define OD 42
#define INV_EXT 0.5f

// K2 GEMM config: kf = f*16 + k (k padded to 16, slot 15 zero), K_total = 2048
#define KT2 64            // 2048 / 32
#define WFA_STRIDE 2056   // halfwords per A row: 2048 + 8 pad (banks: 1028 dw % 32 = 4)
#define WS2_STRIDE 40     // halfwords per (e,k) row of w_s (pad 32->40)

// ws layout (bytes)
#define WS_DEFKP 0
#define WS_FEATBF (3u * 1024u * 1024u)          // 16384*128 bf16 = 4 MB
#define WS_BSW    (7u * 1024u * 1024u)          // 16*64*64*8 bf16 = 1 MB
#define WS_DWT    (8u * 1024u * 1024u)          // 42*1920 fp32 = 322560 B

static __device__ __forceinline__ unsigned short f2bf(float x) {
    union { __hip_bfloat16 h; unsigned short u; } cv;
    cv.h = __float2bfloat16(x);
    return cv.u;
}

// ------------------------- pre-kernels -------------------------
__global__ void cvt_feat(const float* __restrict__ in, unsigned short* __restrict__ out) {
    const int i = (blockIdx.x * 256 + threadIdx.x) * 4;
    if (i >= NQ * FI) return;
    float4 a = *(const float4*)&in[i];
    unsigned int p0 = (unsigned int)f2bf(a.x) | ((unsigned int)f2bf(a.y) << 16);
    unsigned int p1 = (unsigned int)f2bf(a.z) | ((unsigned int)f2bf(a.w) << 16);
    unsigned int* op = (unsigned int*)&out[i];
    op[0] = p0; op[1] = p1;
}

// weight [15][128][256] -> Bsw[nt][kt][lane][8] bf16, kf = f*16+k
__global__ void swz_B(const float* __restrict__ w, unsigned short* __restrict__ Bsw) {
    const int tid = blockIdx.x * 256 + threadIdx.x;   // 65536 total
    const int lane = tid & 63;
    const int kt   = (tid >> 6) & 63;
    const int nt   = tid >> 12;
    const int n    = nt * 16 + (lane & 15);
    const int kbase = kt * 32 + (lane >> 4) * 8;
    unsigned int p[4];
    #pragma unroll
    for (int jj = 0; jj < 4; jj++) {
        unsigned int lo, hi;
        {
            const int kk = kbase + 2 * jj;
            const int f = kk >> 4, k = kk & 15;
            lo = (k < KPN) ? f2bf(w[(k * FI + f) * FO + n]) : 0u;
        }
        {
            const int kk = kbase + 2 * jj + 1;
            const int f = kk >> 4, k = kk & 15;
            hi = (k < KPN) ? f2bf(w[(k * FI + f) * FO + n]) : 0u;
        }
        p[jj] = lo | (hi << 16);
    }
    unsigned int* op = (unsigned int*)&Bsw[tid * 8];
    op[0] = p[0]; op[1] = p[1]; op[2] = p[2]; op[3] = p[3];
}

// dweight [1920][42] -> dwT [42][1920] fp32
__global__ void t_dw(const float* __restrict__ dw, float* __restrict__ dwT) {
    const int tid = blockIdx.x * 256 + threadIdx.x;
    if (tid >= OD * 480) return;
    const int o = tid / 480, c = tid % 480;
    float4 r;
    r.x = dw[(c * 4 + 0) * OD + o];
    r.y = dw[(c * 4 + 1) * OD + o];
    r.z = dw[(c * 4 + 2) * OD + o];
    r.w = dw[(c * 4 + 3) * OD + o];
    *(float4*)&dwT[o * 1920 + c * 4] = r;
}

// ------------------------- stage 1 (fp32): offsets -> defkp -------------------------
__global__ __launch_bounds__(256, 2)
void k1_offsets(const float* __restrict__ query, const float* __restrict__ support,
                const int* __restrict__ neighbors, const float* __restrict__ features,
                const float* __restrict__ kpoints, const float* __restrict__ dwT,
                const float* __restrict__ bias, float* __restrict__ defkp)
{
    __shared__ float wfA[8 * 1924];        // 61568 B, stride 1924 (mod32=4, 16B-aligned)
    __shared__ float w_s[8 * 32 * 16];     // 16384 B
    __shared__ int   nbr_s[8 * 32];
    __shared__ float kp_s[48];

    const int t = threadIdx.x;
    const int qbase = blockIdx.x * 8;

    if (t < 45) kp_s[t] = kpoints[t];

    const int e = t >> 5, n = t & 31;
    const int q = qbase + e;
    const int idx = neighbors[q * NN + n];
    nbr_s[t] = idx;
    const float rx = support[idx * 3 + 0] - query[q * 3 + 0];
    const float ry = support[idx * 3 + 1] - query[q * 3 + 1];
    const float rz = support[idx * 3 + 2] - query[q * 3 + 2];
    __syncthreads();

    // w0 (fp32)
    #pragma unroll
    for (int k = 0; k < KPN; k++) {
        const float dx = rx - kp_s[k * 3 + 0];
        const float dy = ry - kp_s[k * 3 + 1];
        const float dz = rz - kp_s[k * 3 + 2];
        const float w = 1.0f - sqrtf(dx * dx + dy * dy + dz * dz) * INV_EXT;
        w_s[t * 16 + k] = w > 0.f ? w : 0.f;
    }
    __syncthreads();

    // wf0[e][k*128+f] fp32
    {
        const int f = t & 127, g = t >> 7;
        for (int i = 0; i < 4; i++) {
            const int ee = g * 4 + i;
            float acc[KPN];
            #pragma unroll
            for (int k = 0; k < KPN; k++) acc[k] = 0.f;
            const float4* wrow = (const float4*)&w_s[ee * 32 * 16];
            #pragma unroll 2
            for (int nn2 = 0; nn2 < NN; nn2++) {
                const float v = features[nbr_s[ee * 32 + nn2] * FI + f];
                float4 a = wrow[nn2 * 4 + 0], b = wrow[nn2 * 4 + 1];
                float4 c = wrow[nn2 * 4 + 2], d = wrow[nn2 * 4 + 3];
                acc[0] += a.x * v;  acc[1] += a.y * v;  acc[2] += a.z * v;  acc[3] += a.w * v;
                acc[4] += b.x * v;  acc[5] += b.y * v;  acc[6] += b.z * v;  acc[7] += b.w * v;
                acc[8] += c.x * v;  acc[9] += c.y * v;  acc[10] += c.z * v; acc[11] += c.w * v;
                acc[12] += d.x * v; acc[13] += d.y * v; acc[14] += d.z * v;
            }
            #pragma unroll
            for (int k = 0; k < KPN; k++) wfA[ee * 1924 + k * 128 + f] = acc[k];
        }
    }
    __syncthreads();

    // GEMV: offsets[e][o] = sum_kf wf0[e][kf]*dwT[o][kf] + bias[o]
    {
        const int l = t & 31;
        const int o0 = l, o1 = l + 32;
        const bool v1 = (o1 < OD);
        float a0 = 0.f, a1 = 0.f;
        const float4* wf4 = (const float4*)&wfA[e * 1924];
        const float4* d0p = (const float4*)&dwT[o0 * 1920];
        const float4* d1p = (const float4*)&dwT[(v1 ? o1 : o0) * 1920];
        #pragma unroll 4
        for (int c = 0; c < 480; c++) {
            float4 w = wf4[c], x = d0p[c], y = d1p[c];
            a0 += w.x * x.x + w.y * x.y + w.z * x.z + w.w * x.w;
            a1 += w.x * y.x + w.y * y.y + w.z * y.z + w.w * y.w;
        }
        defkp[q * 45 + 3 + o0] = kp_s[3 + o0] + a0 + bias[o0];
        if (v1) defkp[q * 45 + 3 + o1] = kp_s[3 + o1] + a1 + bias[o1];
        if (l < 3) defkp[q * 45 + l] = kp_s[l];
    }
}

// ------------------------- stage 2 (bf16 MFMA): deformable conv -------------------------
__global__ __launch_bounds__(512, 2)
void k2_deform(const float* __restrict__ query, const float* __restrict__ support,
               const int* __restrict__ neighbors, const unsigned short* __restrict__ featbf,
               const unsigned short* __restrict__ Bsw, const float* __restrict__ defkp,
               float* __restrict__ out)
{
    __shared__ unsigned short wfA[16 * WFA_STRIDE];      // 65792 B (A operand, bf16)
    __shared__ unsigned short w_s[16 * 16 * WS2_STRIDE]; // 20480 B (w1^T, bf16)
    __shared__ float dk_s[16 * 45];                      // 2880 B
    __shared__ int   nbr_s[16 * 32];                     // 2048 B

    const int t = threadIdx.x;
    const int qbase = blockIdx.x * 16;

    for (int i = t; i < 16 * 45; i += 512) dk_s[i] = defkp[qbase * 45 + i];

    const int e = t >> 5, n = t & 31;
    const int q = qbase + e;
    const int idx = neighbors[q * NN + n];
    nbr_s[t] = idx;
    const float rx = support[idx * 3 + 0] - query[q * 3 + 0];
    const float ry = support[idx * 3 + 1] - query[q * 3 + 1];
    const float rz = support[idx * 3 + 2] - query[q * 3 + 2];
    __syncthreads();

    // w1 from deformed kernel points -> w_s[e][k][n] bf16 (k=15 row zeroed)
    #pragma unroll
    for (int k = 0; k < KPN; k++) {
        const float dx = rx - dk_s[e * 45 + k * 3 + 0];
        const float dy = ry - dk_s[e * 45 + k * 3 + 1];
        const float dz = rz - dk_s[e * 45 + k * 3 + 2];
        const float w = 1.0f - sqrtf(dx * dx + dy * dy + dz * dz) * INV_EXT;
        w_s[(e * 16 + k) * WS2_STRIDE + n] = f2bf(w > 0.f ? w : 0.f);
    }
    w_s[(e * 16 + 15) * WS2_STRIDE + n] = 0;
    __syncthreads();

    // wf1 via MFMA: per (e, ftile): C[16k x 16f] = W1^T[16k x 32n] * F[32n x 16f]
    {
        const int wave = t >> 6, lane = t & 63;
        const int quad = lane >> 4, low = lane & 15;
        for (int ei = 0; ei < 2; ei++) {
            const int ee = wave * 2 + ei;
            bf16x8 a = *(const bf16x8*)&w_s[(ee * 16 + low) * WS2_STRIDE + quad * 8];
            int rows[8];
            #pragma unroll
            for (int j = 0; j < 8; j++) rows[j] = nbr_s[ee * 32 + quad * 8 + j];
            #pragma unroll
            for (int ft = 0; ft < 8; ft++) {
                unsigned int p[4];
                #pragma unroll
                for (int j = 0; j < 4; j++) {
                    unsigned int lo2 = featbf[rows[2 * j] * FI + ft * 16 + low];
                    unsigned int hi2 = featbf[rows[2 * j + 1] * FI + ft * 16 + low];
                    p[j] = lo2 | (hi2 << 16);
                }
                bf16x8 b;
                {
                    union { unsigned int u[4]; bf16x8 v; } cv;
                    cv.u[0] = p[0]; cv.u[1] = p[1]; cv.u[2] = p[2]; cv.u[3] = p[3];
                    b = cv.v;
                }
                f32x4 acc = {0.f, 0.f, 0.f, 0.f};
                acc = __builtin_amdgcn_mfma_f32_16x16x32_bf16(a, b, acc, 0, 0, 0);
                // store rows k'=quad*4+r at col f=ft*16+low -> wfA[ee][f*16+k']
                const unsigned int w0 = (unsigned int)f2bf(acc[0]) | ((unsigned int)f2bf(acc[1]) << 16);
                const unsigned int w1 = (unsigned int)f2bf(acc[2]) | ((unsigned int)f2bf(acc[3]) << 16);
                unsigned short* wp = &wfA[ee * WFA_STRIDE + (ft * 16 + low) * 16 + quad * 4];
                ((unsigned int*)wp)[0] = w0;
                ((unsigned int*)wp)[1] = w1;
            }
        }
    }
    __syncthreads();

    // GEMM2: out[16 x 256] = wfA[16 x 2048] * Bsw[2048 x 256]
    {
        const int wave = t >> 6, lane = t & 63;
        const int quad = lane >> 4, low = lane & 15;
        const int nt0 = wave * 2, nt1 = nt0 + 1;
        f32x4 acc0 = {0.f, 0.f, 0.f, 0.f}, acc1 = {0.f, 0.f, 0.f, 0.f};
        const bf16x8* Bp = (const bf16x8*)Bsw;
        for (int kt = 0; kt < KT2; kt++) {
            bf16x8 a = *(const bf16x8*)&wfA[low * WFA_STRIDE + kt * 32 + quad * 8];
            bf16x8 b0 = Bp[(nt0 * KT2 + kt) * 64 + lane];
            bf16x8 b1 = Bp[(nt1 * KT2 + kt) * 64 + lane];
            acc0 = __builtin_amdgcn_mfma_f32_16x16x32_bf16(a, b0, acc0, 0, 0, 0);
            acc1 = __builtin_amdgcn_mfma_f32_16x16x32_bf16(a, b1, acc1, 0, 0, 0);
        }
        #pragma unroll
        for (int r = 0; r < 4; r++) {
            const int ee = quad * 4 + r;
            out[(qbase + ee) * FO + nt0 * 16 + low] = acc0[r];
            out[(qbase + ee) * FO + nt1 * 16 + low] = acc1[r];
        }
    }
}

// -------------------------------------------------------------------------
extern "C" void kernel_launch(void* const* d_in, const int* in_sizes, int n_in,
                              void* d_out, int out_size, void* d_ws, size_t ws_size,
                              hipStream_t stream) {
    const float* query     = (const float*)d_in[0];
    const float* support   = (const float*)d_in[1];
    const int*   neighbors = (const int*)  d_in[2];
    const float* features  = (const float*)d_in[3];
    const float* kpoints   = (const float*)d_in[4];
    const float* weight    = (const float*)d_in[5];
    const float* dweight   = (const float*)d_in[6];
    const float* bias      = (const float*)d_in[7];
    float*       out       = (float*)d_out;

    char* ws = (char*)d_ws;
    float*          defkp  = (float*)(ws + WS_DEFKP);
    unsigned short* featbf = (unsigned short*)(ws + WS_FEATBF);
    unsigned short* Bsw    = (unsigned short*)(ws + WS_BSW);
    float*          dwT    = (float*)(ws + WS_DWT);

    cvt_feat<<<(NQ * FI / 4 + 255) / 256, 256, 0, stream>>>(features, featbf);
    swz_B<<<256, 256, 0, stream>>>(weight, Bsw);
    t_dw<<<(OD * 480 + 255) / 256, 256, 0, stream>>>(dweight, dwT);

    k1_offsets<<<NQ / 8, 256, 0, stream>>>(query, support, neighbors, features,
                                           kpoints, dwT, bias, defkp);
    k2_deform<<<NQ / 16, 512, 0, stream>>>(query, support, neighbors, featbf,
                                           Bsw, defkp, out);
}

// Round 3
// 370.223 us; speedup vs baseline: 2.8926x; 2.8926x over previous
//
#include <hip/hip_runtime.h>
#include <hip/hip_bf16.h>
#include <math.h>

typedef __attribute__((ext_vector_type(8))) short bf16x8;
typedef __attribute__((ext_vector_type(4))) float f32x4;

#define NQ 16384
#define NN 32
#define FI 128
#define FO 256
#define KPN 15
#define OD 42
#define INV_EXT 0.5f

// K2 GEMM config: kf = f*16 + k (k padded to 16, slot 15 zero), K_total = 2048
#define KT2 64            // 2048 / 32
#define WFA_STRIDE 2056   // halfwords per A row: 2048 + 8 pad
#define WS2_STRIDE 40     // halfwords per (e,k) row of w_s in k2 (pad 32->40)

// ws layout (bytes)
#define WS_DEFKP  0u                      // 16384*45*4 = 2,949,120
#define WS_FEATBF (3u * 1024u * 1024u)    // 16384*128 bf16 = 4 MB
#define WS_BSW    (7u * 1024u * 1024u)    // 1 MB
#define WS_DWBH   (8u * 1024u * 1024u)    // 3*64*64*8*2 = 196,608
#define WS_DWBL   (WS_DWBH + 196608u)

static __device__ __forceinline__ unsigned short f2bf(float x) {
    union { __hip_bfloat16 h; unsigned short u; } cv;
    cv.h = __float2bfloat16(x);
    return cv.u;
}
static __device__ __forceinline__ float bf2f(unsigned short h) {
    union { unsigned int u; float f; } cv;
    cv.u = ((unsigned int)h) << 16;
    return cv.f;
}

// ------------------------- pre-kernels -------------------------
__global__ void cvt_feat(const float* __restrict__ in, unsigned short* __restrict__ out) {
    const int i = (blockIdx.x * 256 + threadIdx.x) * 4;
    if (i >= NQ * FI) return;
    float4 a = *(const float4*)&in[i];
    unsigned int p0 = (unsigned int)f2bf(a.x) | ((unsigned int)f2bf(a.y) << 16);
    unsigned int p1 = (unsigned int)f2bf(a.z) | ((unsigned int)f2bf(a.w) << 16);
    unsigned int* op = (unsigned int*)&out[i];
    op[0] = p0; op[1] = p1;
}

// weight [15][128][256] -> Bsw[nt][kt][lane][8] bf16, kf = f*16+k  (stage 2)
__global__ void swz_B(const float* __restrict__ w, unsigned short* __restrict__ Bsw) {
    const int tid = blockIdx.x * 256 + threadIdx.x;   // 65536 total
    const int lane = tid & 63;
    const int kt   = (tid >> 6) & 63;
    const int nt   = tid >> 12;
    const int n    = nt * 16 + (lane & 15);
    const int kbase = kt * 32 + (lane >> 4) * 8;
    unsigned int p[4];
    #pragma unroll
    for (int jj = 0; jj < 4; jj++) {
        unsigned int lo, hi;
        {
            const int kk = kbase + 2 * jj;
            const int f = kk >> 4, k = kk & 15;
            lo = (k < KPN) ? f2bf(w[(k * FI + f) * FO + n]) : 0u;
        }
        {
            const int kk = kbase + 2 * jj + 1;
            const int f = kk >> 4, k = kk & 15;
            hi = (k < KPN) ? f2bf(w[(k * FI + f) * FO + n]) : 0u;
        }
        p[jj] = lo | (hi << 16);
    }
    unsigned int* op = (unsigned int*)&Bsw[tid * 8];
    op[0] = p[0]; op[1] = p[1]; op[2] = p[2]; op[3] = p[3];
}

// dweight [15][128][42] -> split-bf16 B-fragments dwB_{hi,lo}[nt(3)][kt(64)][lane(64)][8]
__global__ void build_dwB(const float* __restrict__ dw,
                          unsigned short* __restrict__ hi,
                          unsigned short* __restrict__ lo) {
    const int tid = blockIdx.x * 256 + threadIdx.x;   // 12288 total
    if (tid >= 3 * 64 * 64) return;
    const int lane = tid & 63;
    const int kt   = (tid >> 6) & 63;
    const int nt   = tid >> 12;
    const int o    = nt * 16 + (lane & 15);
    const int kbase = kt * 32 + (lane >> 4) * 8;
    #pragma unroll
    for (int j = 0; j < 8; j++) {
        const int kf = kbase + j;
        const int f = kf >> 4, k = kf & 15;
        float v = (k < KPN && o < OD) ? dw[(k * FI + f) * OD + o] : 0.f;
        unsigned short h = f2bf(v);
        hi[tid * 8 + j] = h;
        lo[tid * 8 + j] = f2bf(v - bf2f(h));
    }
}

// ------------------------- stage 1: offsets via split-bf16 MFMA -------------------------
// E=8 queries/block, 256 threads (4 waves).  fp32-quality via hi/lo 3-product MFMA.
__global__ __launch_bounds__(256)
void k1_offsets(const float* __restrict__ query, const float* __restrict__ support,
                const int* __restrict__ neighbors, const float* __restrict__ features,
                const float* __restrict__ kpoints,
                const unsigned short* __restrict__ dwB_hi,
                const unsigned short* __restrict__ dwB_lo,
                const float* __restrict__ bias, float* __restrict__ defkp)
{
    __shared__ unsigned short wfA_hi[8 * 2056];   // 32896 B
    __shared__ unsigned short wfA_lo[8 * 2056];   // 32896 B
    __shared__ float w_s[256 * 17];               // 17408 B (stride 17: conflict-free)
    __shared__ int   nbr_s[256];
    __shared__ float kp_s[48];

    const int t = threadIdx.x;
    const int qbase = blockIdx.x * 8;
    if (t < 45) kp_s[t] = kpoints[t];

    const int e = t >> 5, n = t & 31;
    const int q = qbase + e;
    const int idx = neighbors[q * NN + n];
    nbr_s[t] = idx;
    const float rx = support[idx * 3 + 0] - query[q * 3 + 0];
    const float ry = support[idx * 3 + 1] - query[q * 3 + 1];
    const float rz = support[idx * 3 + 2] - query[q * 3 + 2];
    __syncthreads();

    // w0 fp32 -> w_s[(e*32+n)*17 + k], k=15 slot zero
    #pragma unroll
    for (int k = 0; k < KPN; k++) {
        const float dx = rx - kp_s[k * 3 + 0];
        const float dy = ry - kp_s[k * 3 + 1];
        const float dz = rz - kp_s[k * 3 + 2];
        const float w = 1.0f - sqrtf(dx * dx + dy * dy + dz * dz) * INV_EXT;
        w_s[t * 17 + k] = w > 0.f ? w : 0.f;
    }
    w_s[t * 17 + 15] = 0.f;
    __syncthreads();

    const int wave = t >> 6, lane = t & 63;
    const int quad = lane >> 4, low = lane & 15;

    // Phase B: wf0[e][kf] = sum_n w0[e][n][k] * feat[n][f]  (split-bf16, fp32 C)
    for (int ei = 0; ei < 2; ei++) {
        const int ee = wave * 2 + ei;
        union { unsigned short u[8]; bf16x8 v; } ah, al;
        int rows[8];
        #pragma unroll
        for (int j = 0; j < 8; j++) {
            const float av = w_s[(ee * 32 + quad * 8 + j) * 17 + low];
            const unsigned short h = f2bf(av);
            ah.u[j] = h;
            al.u[j] = f2bf(av - bf2f(h));
            rows[j] = nbr_s[ee * 32 + quad * 8 + j];
        }
        #pragma unroll
        for (int ft = 0; ft < 8; ft++) {
            union { unsigned short u[8]; bf16x8 v; } bh, bl;
            #pragma unroll
            for (int j = 0; j < 8; j++) {
                const float v = features[rows[j] * FI + ft * 16 + low];
                const unsigned short h = f2bf(v);
                bh.u[j] = h;
                bl.u[j] = f2bf(v - bf2f(h));
            }
            f32x4 acc = {0.f, 0.f, 0.f, 0.f};
            acc = __builtin_amdgcn_mfma_f32_16x16x32_bf16(al.v, bh.v, acc, 0, 0, 0);
            acc = __builtin_amdgcn_mfma_f32_16x16x32_bf16(ah.v, bl.v, acc, 0, 0, 0);
            acc = __builtin_amdgcn_mfma_f32_16x16x32_bf16(ah.v, bh.v, acc, 0, 0, 0);
            // C element (row k'=quad*4+r, col f=ft*16+low) -> kf = f*16+k'
            const int kfb = (ft * 16 + low) * 16 + quad * 4;
            const unsigned short h0 = f2bf(acc[0]), h1 = f2bf(acc[1]);
            const unsigned short h2 = f2bf(acc[2]), h3 = f2bf(acc[3]);
            unsigned int* ph = (unsigned int*)&wfA_hi[ee * 2056 + kfb];
            ph[0] = (unsigned int)h0 | ((unsigned int)h1 << 16);
            ph[1] = (unsigned int)h2 | ((unsigned int)h3 << 16);
            unsigned int* pl = (unsigned int*)&wfA_lo[ee * 2056 + kfb];
            pl[0] = (unsigned int)f2bf(acc[0] - bf2f(h0)) |
                    ((unsigned int)f2bf(acc[1] - bf2f(h1)) << 16);
            pl[1] = (unsigned int)f2bf(acc[2] - bf2f(h2)) |
                    ((unsigned int)f2bf(acc[3] - bf2f(h3)) << 16);
        }
    }
    __syncthreads();

    // Phase C: feat0[8e x 48o] = wfA[8e x 2048] * dwB[2048 x 48]  (split-bf16)
    if (wave < 3) {
        const int nt = wave;
        f32x4 acc = {0.f, 0.f, 0.f, 0.f};
        const bf16x8* Bh = (const bf16x8*)dwB_hi;
        const bf16x8* Bl = (const bf16x8*)dwB_lo;
        const int arow = (low & 7) * 2056;      // rows 8..15 duplicate 0..7 (ignored)
        for (int kt = 0; kt < KT2; kt++) {
            bf16x8 a_h = *(const bf16x8*)&wfA_hi[arow + kt * 32 + quad * 8];
            bf16x8 a_l = *(const bf16x8*)&wfA_lo[arow + kt * 32 + quad * 8];
            bf16x8 b_h = Bh[(nt * KT2 + kt) * 64 + lane];
            bf16x8 b_l = Bl[(nt * KT2 + kt) * 64 + lane];
            acc = __builtin_amdgcn_mfma_f32_16x16x32_bf16(a_l, b_h, acc, 0, 0, 0);
            acc = __builtin_amdgcn_mfma_f32_16x16x32_bf16(a_h, b_l, acc, 0, 0, 0);
            acc = __builtin_amdgcn_mfma_f32_16x16x32_bf16(a_h, b_h, acc, 0, 0, 0);
        }
        const int o = nt * 16 + low;
        if (quad < 2 && o < OD) {
            const float bo = bias[o] + kp_s[3 + o];
            #pragma unroll
            for (int r = 0; r < 4; r++) {
                const int ee = quad * 4 + r;                 // C row = e
                defkp[(qbase + ee) * 45 + 3 + o] = bo + acc[r];
            }
        }
    } else if (lane < 24) {
        defkp[(qbase + lane / 3) * 45 + (lane % 3)] = kp_s[lane % 3];
    }
}

// ------------------------- stage 2 (bf16 MFMA): deformable conv -------------------------
__global__ __launch_bounds__(512, 2)
void k2_deform(const float* __restrict__ query, const float* __restrict__ support,
               const int* __restrict__ neighbors, const unsigned short* __restrict__ featbf,
               const unsigned short* __restrict__ Bsw, const float* __restrict__ defkp,
               float* __restrict__ out)
{
    __shared__ unsigned short wfA[16 * WFA_STRIDE];      // 65792 B
    __shared__ unsigned short w_s[16 * 16 * WS2_STRIDE]; // 20480 B
    __shared__ float dk_s[16 * 45];
    __shared__ int   nbr_s[16 * 32];

    const int t = threadIdx.x;
    const int qbase = blockIdx.x * 16;

    for (int i = t; i < 16 * 45; i += 512) dk_s[i] = defkp[qbase * 45 + i];

    const int e = t >> 5, n = t & 31;
    const int q = qbase + e;
    const int idx = neighbors[q * NN + n];
    nbr_s[t] = idx;
    const float rx = support[idx * 3 + 0] - query[q * 3 + 0];
    const float ry = support[idx * 3 + 1] - query[q * 3 + 1];
    const float rz = support[idx * 3 + 2] - query[q * 3 + 2];
    __syncthreads();

    #pragma unroll
    for (int k = 0; k < KPN; k++) {
        const float dx = rx - dk_s[e * 45 + k * 3 + 0];
        const float dy = ry - dk_s[e * 45 + k * 3 + 1];
        const float dz = rz - dk_s[e * 45 + k * 3 + 2];
        const float w = 1.0f - sqrtf(dx * dx + dy * dy + dz * dz) * INV_EXT;
        w_s[(e * 16 + k) * WS2_STRIDE + n] = f2bf(w > 0.f ? w : 0.f);
    }
    w_s[(e * 16 + 15) * WS2_STRIDE + n] = 0;
    __syncthreads();

    {
        const int wave = t >> 6, lane = t & 63;
        const int quad = lane >> 4, low = lane & 15;
        for (int ei = 0; ei < 2; ei++) {
            const int ee = wave * 2 + ei;
            bf16x8 a = *(const bf16x8*)&w_s[(ee * 16 + low) * WS2_STRIDE + quad * 8];
            int rows[8];
            #pragma unroll
            for (int j = 0; j < 8; j++) rows[j] = nbr_s[ee * 32 + quad * 8 + j];
            #pragma unroll
            for (int ft = 0; ft < 8; ft++) {
                unsigned int p[4];
                #pragma unroll
                for (int j = 0; j < 4; j++) {
                    unsigned int lo2 = featbf[rows[2 * j] * FI + ft * 16 + low];
                    unsigned int hi2 = featbf[rows[2 * j + 1] * FI + ft * 16 + low];
                    p[j] = lo2 | (hi2 << 16);
                }
                bf16x8 b;
                {
                    union { unsigned int u[4]; bf16x8 v; } cv;
                    cv.u[0] = p[0]; cv.u[1] = p[1]; cv.u[2] = p[2]; cv.u[3] = p[3];
                    b = cv.v;
                }
                f32x4 acc = {0.f, 0.f, 0.f, 0.f};
                acc = __builtin_amdgcn_mfma_f32_16x16x32_bf16(a, b, acc, 0, 0, 0);
                const unsigned int w0 = (unsigned int)f2bf(acc[0]) | ((unsigned int)f2bf(acc[1]) << 16);
                const unsigned int w1 = (unsigned int)f2bf(acc[2]) | ((unsigned int)f2bf(acc[3]) << 16);
                unsigned short* wp = &wfA[ee * WFA_STRIDE + (ft * 16 + low) * 16 + quad * 4];
                ((unsigned int*)wp)[0] = w0;
                ((unsigned int*)wp)[1] = w1;
            }
        }
    }
    __syncthreads();

    {
        const int wave = t >> 6, lane = t & 63;
        const int quad = lane >> 4, low = lane & 15;
        const int nt0 = wave * 2, nt1 = nt0 + 1;
        f32x4 acc0 = {0.f, 0.f, 0.f, 0.f}, acc1 = {0.f, 0.f, 0.f, 0.f};
        const bf16x8* Bp = (const bf16x8*)Bsw;
        for (int kt = 0; kt < KT2; kt++) {
            bf16x8 a = *(const bf16x8*)&wfA[low * WFA_STRIDE + kt * 32 + quad * 8];
            bf16x8 b0 = Bp[(nt0 * KT2 + kt) * 64 + lane];
            bf16x8 b1 = Bp[(nt1 * KT2 + kt) * 64 + lane];
            acc0 = __builtin_amdgcn_mfma_f32_16x16x32_bf16(a, b0, acc0, 0, 0, 0);
            acc1 = __builtin_amdgcn_mfma_f32_16x16x32_bf16(a, b1, acc1, 0, 0, 0);
        }
        #pragma unroll
        for (int r = 0; r < 4; r++) {
            const int ee = quad * 4 + r;
            out[(qbase + ee) * FO + nt0 * 16 + low] = acc0[r];
            out[(qbase + ee) * FO + nt1 * 16 + low] = acc1[r];
        }
    }
}

// -------------------------------------------------------------------------
extern "C" void kernel_launch(void* const* d_in, const int* in_sizes, int n_in,
                              void* d_out, int out_size, void* d_ws, size_t ws_size,
                              hipStream_t stream) {
    const float* query     = (const float*)d_in[0];
    const float* support   = (const float*)d_in[1];
    const int*   neighbors = (const int*)  d_in[2];
    const float* features  = (const float*)d_in[3];
    const float* kpoints   = (const float*)d_in[4];
    const float* weight    = (const float*)d_in[5];
    const float* dweight   = (const float*)d_in[6];
    const float* bias      = (const float*)d_in[7];
    float*       out       = (float*)d_out;

    char* ws = (char*)d_ws;
    float*          defkp  = (float*)(ws + WS_DEFKP);
    unsigned short* featbf = (unsigned short*)(ws + WS_FEATBF);
    unsigned short* Bsw    = (unsigned short*)(ws + WS_BSW);
    unsigned short* dwBh   = (unsigned short*)(ws + WS_DWBH);
    unsigned short* dwBl   = (unsigned short*)(ws + WS_DWBL);

    cvt_feat<<<(NQ * FI / 4 + 255) / 256, 256, 0, stream>>>(features, featbf);
    swz_B<<<256, 256, 0, stream>>>(weight, Bsw);
    build_dwB<<<48, 256, 0, stream>>>(dweight, dwBh, dwBl);

    k1_offsets<<<NQ / 8, 256, 0, stream>>>(query, support, neighbors, features,
                                           kpoints, dwBh, dwBl, bias, defkp);
    k2_deform<<<NQ / 16, 512, 0, stream>>>(query, support, neighbors, featbf,
                                           Bsw, defkp, out);
}

// Round 4
// 254.533 us; speedup vs baseline: 4.2074x; 1.4545x over previous
//
#include <hip/hip_runtime.h>
#include <hip/hip_bf16.h>
#include <math.h>

typedef __attribute__((ext_vector_type(8))) short bf16x8;
typedef __attribute__((ext_vector_type(4))) float f32x4;

#define NQ 16384
#define NN 32
#define FI 128
#define FO 256
#define KPN 15
#define OD 42
#define INV_EXT 0.5f

#define KT2 64            // 2048 / 32
#define WFA_STRIDE 2056   // halfwords per A row: 2048 + 8 pad (4112 B, 16B-aligned)

// ws layout (bytes)
#define WS_DEFKP  0u                      // 16384*45*4 = 2,949,120
#define WS_FEATBF (3u * 1024u * 1024u)    // 16384*128 bf16 = 4 MB
#define WS_BSW    (7u * 1024u * 1024u)    // 1 MB
#define WS_DWBH   (8u * 1024u * 1024u)    // 196,608
#define WS_DWBL   (WS_DWBH + 196608u)

static __device__ __forceinline__ unsigned short f2bf(float x) {
    union { __hip_bfloat16 h; unsigned short u; } cv;
    cv.h = __float2bfloat16(x);
    return cv.u;
}
static __device__ __forceinline__ float bf2f(unsigned short h) {
    union { unsigned int u; float f; } cv;
    cv.u = ((unsigned int)h) << 16;
    return cv.f;
}

// ------------------------- pre-kernels -------------------------
__global__ void cvt_feat(const float* __restrict__ in, unsigned short* __restrict__ out) {
    const int i = (blockIdx.x * 256 + threadIdx.x) * 4;
    if (i >= NQ * FI) return;
    float4 a = *(const float4*)&in[i];
    unsigned int p0 = (unsigned int)f2bf(a.x) | ((unsigned int)f2bf(a.y) << 16);
    unsigned int p1 = (unsigned int)f2bf(a.z) | ((unsigned int)f2bf(a.w) << 16);
    unsigned int* op = (unsigned int*)&out[i];
    op[0] = p0; op[1] = p1;
}

// weight [15][128][256] -> Bsw[nt][kt][lane][8] bf16, kf = f*16+k  (stage 2)
__global__ void swz_B(const float* __restrict__ w, unsigned short* __restrict__ Bsw) {
    const int tid = blockIdx.x * 256 + threadIdx.x;   // 65536 total
    const int lane = tid & 63;
    const int kt   = (tid >> 6) & 63;
    const int nt   = tid >> 12;
    const int n    = nt * 16 + (lane & 15);
    const int kbase = kt * 32 + (lane >> 4) * 8;
    unsigned int p[4];
    #pragma unroll
    for (int jj = 0; jj < 4; jj++) {
        unsigned int lo, hi;
        {
            const int kk = kbase + 2 * jj;
            const int f = kk >> 4, k = kk & 15;
            lo = (k < KPN) ? f2bf(w[(k * FI + f) * FO + n]) : 0u;
        }
        {
            const int kk = kbase + 2 * jj + 1;
            const int f = kk >> 4, k = kk & 15;
            hi = (k < KPN) ? f2bf(w[(k * FI + f) * FO + n]) : 0u;
        }
        p[jj] = lo | (hi << 16);
    }
    unsigned int* op = (unsigned int*)&Bsw[tid * 8];
    op[0] = p[0]; op[1] = p[1]; op[2] = p[2]; op[3] = p[3];
}

// dweight [15][128][42] -> split-bf16 B-fragments dwB_{hi,lo}[nt(3)][kt(64)][lane(64)][8]
__global__ void build_dwB(const float* __restrict__ dw,
                          unsigned short* __restrict__ hi,
                          unsigned short* __restrict__ lo) {
    const int tid = blockIdx.x * 256 + threadIdx.x;   // 12288 total
    if (tid >= 3 * 64 * 64) return;
    const int lane = tid & 63;
    const int kt   = (tid >> 6) & 63;
    const int nt   = tid >> 12;
    const int o    = nt * 16 + (lane & 15);
    const int kbase = kt * 32 + (lane >> 4) * 8;
    #pragma unroll
    for (int j = 0; j < 8; j++) {
        const int kf = kbase + j;
        const int f = kf >> 4, k = kf & 15;
        float v = (k < KPN && o < OD) ? dw[(k * FI + f) * OD + o] : 0.f;
        unsigned short h = f2bf(v);
        hi[tid * 8 + j] = h;
        lo[tid * 8 + j] = f2bf(v - bf2f(h));
    }
}

// ------------------------- stage 1: offsets via split-bf16 MFMA -------------------------
// E=8 queries/block, 256 threads (4 waves). LDS 68.5 KB -> 2 blocks/CU.
// w0 recomputed per-consumer-lane from rel (no w_s staging array).
__global__ __launch_bounds__(256, 2)
void k1_offsets(const float* __restrict__ query, const float* __restrict__ support,
                const int* __restrict__ neighbors, const float* __restrict__ features,
                const float* __restrict__ kpoints,
                const unsigned short* __restrict__ dwB_hi,
                const unsigned short* __restrict__ dwB_lo,
                const float* __restrict__ bias, float* __restrict__ defkp)
{
    __shared__ unsigned short wfA_hi[8 * WFA_STRIDE];   // 32896 B
    __shared__ unsigned short wfA_lo[8 * WFA_STRIDE];   // 32896 B
    __shared__ float relx[256], rely[256], relz[256];   // 3072 B, conflict-free
    __shared__ int   nbr_s[256];
    __shared__ float kp_s[48];

    const int t = threadIdx.x;
    const int qbase = blockIdx.x * 8;
    if (t < 45) kp_s[t] = kpoints[t];
    if (t >= 45 && t < 48) kp_s[t] = 0.f;

    const int e = t >> 5, n = t & 31;
    const int q = qbase + e;
    const int idx = neighbors[q * NN + n];
    nbr_s[t] = idx;
    relx[t] = support[idx * 3 + 0] - query[q * 3 + 0];
    rely[t] = support[idx * 3 + 1] - query[q * 3 + 1];
    relz[t] = support[idx * 3 + 2] - query[q * 3 + 2];
    __syncthreads();

    const int wave = t >> 6, lane = t & 63;
    const int quad = lane >> 4, low = lane & 15;

    // Phase B: wf0[e][kf] = sum_n w0[e][n][k] * feat[n][f]  (split-bf16, fp32 C)
    {
        const int kb = (low < KPN) ? low * 3 : 0;
        const float kx = kp_s[kb + 0], ky = kp_s[kb + 1], kz = kp_s[kb + 2];
        for (int ei = 0; ei < 2; ei++) {
            const int ee = wave * 2 + ei;
            union { unsigned short u[8]; bf16x8 v; } ah, al;
            int rows[8];
            #pragma unroll
            for (int j = 0; j < 8; j++) {
                const int ni = ee * 32 + quad * 8 + j;
                rows[j] = nbr_s[ni];
                const float dx = relx[ni] - kx;
                const float dy = rely[ni] - ky;
                const float dz = relz[ni] - kz;
                const float d = sqrtf(dx * dx + dy * dy + dz * dz);
                float w = 1.0f - d * INV_EXT;
                w = (low < KPN && w > 0.f) ? w : 0.f;
                const unsigned short h = f2bf(w);
                ah.u[j] = h;
                al.u[j] = f2bf(w - bf2f(h));
            }
            #pragma unroll
            for (int ft = 0; ft < 8; ft++) {
                union { unsigned short u[8]; bf16x8 v; } bh, bl;
                #pragma unroll
                for (int j = 0; j < 8; j++) {
                    const float v = features[rows[j] * FI + ft * 16 + low];
                    const unsigned short h = f2bf(v);
                    bh.u[j] = h;
                    bl.u[j] = f2bf(v - bf2f(h));
                }
                f32x4 acc = {0.f, 0.f, 0.f, 0.f};
                acc = __builtin_amdgcn_mfma_f32_16x16x32_bf16(al.v, bh.v, acc, 0, 0, 0);
                acc = __builtin_amdgcn_mfma_f32_16x16x32_bf16(ah.v, bl.v, acc, 0, 0, 0);
                acc = __builtin_amdgcn_mfma_f32_16x16x32_bf16(ah.v, bh.v, acc, 0, 0, 0);
                // C element (row k'=quad*4+r, col f=ft*16+low) -> kf = f*16+k'
                const int kfb = (ft * 16 + low) * 16 + quad * 4;
                const unsigned short h0 = f2bf(acc[0]), h1 = f2bf(acc[1]);
                const unsigned short h2 = f2bf(acc[2]), h3 = f2bf(acc[3]);
                unsigned int* ph = (unsigned int*)&wfA_hi[ee * WFA_STRIDE + kfb];
                ph[0] = (unsigned int)h0 | ((unsigned int)h1 << 16);
                ph[1] = (unsigned int)h2 | ((unsigned int)h3 << 16);
                unsigned int* pl = (unsigned int*)&wfA_lo[ee * WFA_STRIDE + kfb];
                pl[0] = (unsigned int)f2bf(acc[0] - bf2f(h0)) |
                        ((unsigned int)f2bf(acc[1] - bf2f(h1)) << 16);
                pl[1] = (unsigned int)f2bf(acc[2] - bf2f(h2)) |
                        ((unsigned int)f2bf(acc[3] - bf2f(h3)) << 16);
            }
        }
    }
    __syncthreads();

    // Phase C: feat0[8e x 48o] = wfA[8e x 2048] * dwB[2048 x 48]  (split-bf16)
    if (wave < 3) {
        const int nt = wave;
        f32x4 acc = {0.f, 0.f, 0.f, 0.f};
        const bf16x8* Bh = (const bf16x8*)dwB_hi;
        const bf16x8* Bl = (const bf16x8*)dwB_lo;
        const int arow = (low & 7) * WFA_STRIDE;   // rows 8..15 duplicate 0..7
        for (int kt = 0; kt < KT2; kt++) {
            bf16x8 a_h = *(const bf16x8*)&wfA_hi[arow + kt * 32 + quad * 8];
            bf16x8 a_l = *(const bf16x8*)&wfA_lo[arow + kt * 32 + quad * 8];
            bf16x8 b_h = Bh[(nt * KT2 + kt) * 64 + lane];
            bf16x8 b_l = Bl[(nt * KT2 + kt) * 64 + lane];
            acc = __builtin_amdgcn_mfma_f32_16x16x32_bf16(a_l, b_h, acc, 0, 0, 0);
            acc = __builtin_amdgcn_mfma_f32_16x16x32_bf16(a_h, b_l, acc, 0, 0, 0);
            acc = __builtin_amdgcn_mfma_f32_16x16x32_bf16(a_h, b_h, acc, 0, 0, 0);
        }
        const int o = nt * 16 + low;
        if (quad < 2 && o < OD) {
            const float bo = bias[o] + kp_s[3 + o];
            #pragma unroll
            for (int r = 0; r < 4; r++) {
                const int ee = quad * 4 + r;                 // C row = e
                defkp[(qbase + ee) * 45 + 3 + o] = bo + acc[r];
            }
        }
    } else if (lane < 24) {
        defkp[(qbase + lane / 3) * 45 + (lane % 3)] = kp_s[lane % 3];
    }
}

// ------------------------- stage 2 (bf16 MFMA): deformable conv -------------------------
// E=16 queries, 512 threads. LDS 75 KB -> 2 blocks/CU (16 waves).
__global__ __launch_bounds__(512, 4)
void k2_deform(const float* __restrict__ query, const float* __restrict__ support,
               const int* __restrict__ neighbors, const unsigned short* __restrict__ featbf,
               const unsigned short* __restrict__ Bsw, const float* __restrict__ defkp,
               float* __restrict__ out)
{
    __shared__ unsigned short wfA[16 * WFA_STRIDE];      // 65792 B
    __shared__ float relx[512], rely[512], relz[512];    // 6144 B
    __shared__ float dk_s[16 * 45];                      // 2880 B
    __shared__ int   nbr_s[512];                         // 2048 B

    const int t = threadIdx.x;
    const int qbase = blockIdx.x * 16;

    for (int i = t; i < 16 * 45; i += 512) dk_s[i] = defkp[qbase * 45 + i];

    const int e = t >> 5, n = t & 31;
    const int q = qbase + e;
    const int idx = neighbors[q * NN + n];
    nbr_s[t] = idx;
    relx[t] = support[idx * 3 + 0] - query[q * 3 + 0];
    rely[t] = support[idx * 3 + 1] - query[q * 3 + 1];
    relz[t] = support[idx * 3 + 2] - query[q * 3 + 2];
    __syncthreads();

    const int wave = t >> 6, lane = t & 63;
    const int quad = lane >> 4, low = lane & 15;

    // wf1 via MFMA; A-frag (w1^T) recomputed per lane from rel + def_kp
    {
        const int kb = (low < KPN) ? low * 3 : 0;
        for (int ei = 0; ei < 2; ei++) {
            const int ee = wave * 2 + ei;
            const float kx = dk_s[ee * 45 + kb + 0];
            const float ky = dk_s[ee * 45 + kb + 1];
            const float kz = dk_s[ee * 45 + kb + 2];
            union { unsigned short u[8]; bf16x8 v; } a;
            int rows[8];
            #pragma unroll
            for (int j = 0; j < 8; j++) {
                const int ni = ee * 32 + quad * 8 + j;
                rows[j] = nbr_s[ni];
                const float dx = relx[ni] - kx;
                const float dy = rely[ni] - ky;
                const float dz = relz[ni] - kz;
                const float d = sqrtf(dx * dx + dy * dy + dz * dz);
                float w = 1.0f - d * INV_EXT;
                w = (low < KPN && w > 0.f) ? w : 0.f;
                a.u[j] = f2bf(w);
            }
            #pragma unroll
            for (int ft = 0; ft < 8; ft++) {
                unsigned int p[4];
                #pragma unroll
                for (int j = 0; j < 4; j++) {
                    unsigned int lo2 = featbf[rows[2 * j] * FI + ft * 16 + low];
                    unsigned int hi2 = featbf[rows[2 * j + 1] * FI + ft * 16 + low];
                    p[j] = lo2 | (hi2 << 16);
                }
                bf16x8 b;
                {
                    union { unsigned int u[4]; bf16x8 v; } cv;
                    cv.u[0] = p[0]; cv.u[1] = p[1]; cv.u[2] = p[2]; cv.u[3] = p[3];
                    b = cv.v;
                }
                f32x4 acc = {0.f, 0.f, 0.f, 0.f};
                acc = __builtin_amdgcn_mfma_f32_16x16x32_bf16(a.v, b, acc, 0, 0, 0);
                const unsigned int w0 = (unsigned int)f2bf(acc[0]) | ((unsigned int)f2bf(acc[1]) << 16);
                const unsigned int w1 = (unsigned int)f2bf(acc[2]) | ((unsigned int)f2bf(acc[3]) << 16);
                unsigned short* wp = &wfA[ee * WFA_STRIDE + (ft * 16 + low) * 16 + quad * 4];
                ((unsigned int*)wp)[0] = w0;
                ((unsigned int*)wp)[1] = w1;
            }
        }
    }
    __syncthreads();

    // GEMM2: out[16 x 256] = wfA[16 x 2048] * Bsw[2048 x 256]
    {
        const int nt0 = wave * 2, nt1 = nt0 + 1;
        f32x4 acc0 = {0.f, 0.f, 0.f, 0.f}, acc1 = {0.f, 0.f, 0.f, 0.f};
        const bf16x8* Bp = (const bf16x8*)Bsw;
        for (int kt = 0; kt < KT2; kt++) {
            bf16x8 a = *(const bf16x8*)&wfA[low * WFA_STRIDE + kt * 32 + quad * 8];
            bf16x8 b0 = Bp[(nt0 * KT2 + kt) * 64 + lane];
            bf16x8 b1 = Bp[(nt1 * KT2 + kt) * 64 + lane];
            acc0 = __builtin_amdgcn_mfma_f32_16x16x32_bf16(a, b0, acc0, 0, 0, 0);
            acc1 = __builtin_amdgcn_mfma_f32_16x16x32_bf16(a, b1, acc1, 0, 0, 0);
        }
        #pragma unroll
        for (int r = 0; r < 4; r++) {
            const int ee = quad * 4 + r;
            out[(qbase + ee) * FO + nt0 * 16 + low] = acc0[r];
            out[(qbase + ee) * FO + nt1 * 16 + low] = acc1[r];
        }
    }
}

// -------------------------------------------------------------------------
extern "C" void kernel_launch(void* const* d_in, const int* in_sizes, int n_in,
                              void* d_out, int out_size, void* d_ws, size_t ws_size,
                              hipStream_t stream) {
    const float* query     = (const float*)d_in[0];
    const float* support   = (const float*)d_in[1];
    const int*   neighbors = (const int*)  d_in[2];
    const float* features  = (const float*)d_in[3];
    const float* kpoints   = (const float*)d_in[4];
    const float* weight    = (const float*)d_in[5];
    const float* dweight   = (const float*)d_in[6];
    const float* bias      = (const float*)d_in[7];
    float*       out       = (float*)d_out;

    char* ws = (char*)d_ws;
    float*          defkp  = (float*)(ws + WS_DEFKP);
    unsigned short* featbf = (unsigned short*)(ws + WS_FEATBF);
    unsigned short* Bsw    = (unsigned short*)(ws + WS_BSW);
    unsigned short* dwBh   = (unsigned short*)(ws + WS_DWBH);
    unsigned short* dwBl   = (unsigned short*)(ws + WS_DWBL);

    cvt_feat<<<(NQ * FI / 4 + 255) / 256, 256, 0, stream>>>(features, featbf);
    swz_B<<<256, 256, 0, stream>>>(weight, Bsw);
    build_dwB<<<48, 256, 0, stream>>>(dweight, dwBh, dwBl);

    k1_offsets<<<NQ / 8, 256, 0, stream>>>(query, support, neighbors, features,
                                           kpoints, dwBh, dwBl, bias, defkp);
    k2_deform<<<NQ / 16, 512, 0, stream>>>(query, support, neighbors, featbf,
                                           Bsw, defkp, out);
}

// Round 5
// 194.596 us; speedup vs baseline: 5.5033x; 1.3080x over previous
//
#include <hip/hip_runtime.h>
#include <hip/hip_bf16.h>
#include <math.h>

typedef __attribute__((ext_vector_type(8))) short bf16x8;
typedef __attribute__((ext_vector_type(4))) float f32x4;

#define NQ 16384
#define NN 32
#define FI 128
#define FO 256
#define KPN 15
#define OD 42
#define INV_EXT 0.5f

#define KT2 64            // 2048 / 32
#define WFA_STRIDE 2056   // halfwords per A row: 2048 + 8 pad (4112 B, 16B-aligned)

// ws layout (bytes)
#define WS_DEFKP  0u                      // 16384*45*4 = 2,949,120
#define WS_FEATBF (3u * 1024u * 1024u)    // 16384*128 bf16 hi = 4 MB
#define WS_BSW    (7u * 1024u * 1024u)    // 1 MB
#define WS_DWBH   (8u * 1024u * 1024u)    // 196,608
#define WS_DWBL   (WS_DWBH + 196608u)
#define WS_FEATPK (9u * 1024u * 1024u)    // 16384*128 u32 (hi|lo<<16) = 8 MB

static __device__ __forceinline__ unsigned short f2bf(float x) {
    union { __hip_bfloat16 h; unsigned short u; } cv;
    cv.h = __float2bfloat16(x);
    return cv.u;
}
static __device__ __forceinline__ float bf2f(unsigned short h) {
    union { unsigned int u; float f; } cv;
    cv.u = ((unsigned int)h) << 16;
    return cv.f;
}

// ------------------------- pre-kernels -------------------------
// features fp32 -> featbf (hi bf16, for k2) and featpk (hi|lo<<16 u32, for k1)
__global__ void prep_feat(const float* __restrict__ in,
                          unsigned short* __restrict__ fbf,
                          unsigned int* __restrict__ fpk) {
    const int i = (blockIdx.x * 256 + threadIdx.x) * 4;
    if (i >= NQ * FI) return;
    float4 a = *(const float4*)&in[i];
    unsigned short h0 = f2bf(a.x), h1 = f2bf(a.y), h2 = f2bf(a.z), h3 = f2bf(a.w);
    unsigned int* bp = (unsigned int*)&fbf[i];
    bp[0] = (unsigned int)h0 | ((unsigned int)h1 << 16);
    bp[1] = (unsigned int)h2 | ((unsigned int)h3 << 16);
    fpk[i + 0] = (unsigned int)h0 | ((unsigned int)f2bf(a.x - bf2f(h0)) << 16);
    fpk[i + 1] = (unsigned int)h1 | ((unsigned int)f2bf(a.y - bf2f(h1)) << 16);
    fpk[i + 2] = (unsigned int)h2 | ((unsigned int)f2bf(a.z - bf2f(h2)) << 16);
    fpk[i + 3] = (unsigned int)h3 | ((unsigned int)f2bf(a.w - bf2f(h3)) << 16);
}

// weight [15][128][256] -> Bsw[nt][kt][lane][8] bf16, kf = f*16+k  (stage 2)
__global__ void swz_B(const float* __restrict__ w, unsigned short* __restrict__ Bsw) {
    const int tid = blockIdx.x * 256 + threadIdx.x;   // 65536 total
    const int lane = tid & 63;
    const int kt   = (tid >> 6) & 63;
    const int nt   = tid >> 12;
    const int n    = nt * 16 + (lane & 15);
    const int kbase = kt * 32 + (lane >> 4) * 8;
    unsigned int p[4];
    #pragma unroll
    for (int jj = 0; jj < 4; jj++) {
        unsigned int lo, hi;
        {
            const int kk = kbase + 2 * jj;
            const int f = kk >> 4, k = kk & 15;
            lo = (k < KPN) ? f2bf(w[(k * FI + f) * FO + n]) : 0u;
        }
        {
            const int kk = kbase + 2 * jj + 1;
            const int f = kk >> 4, k = kk & 15;
            hi = (k < KPN) ? f2bf(w[(k * FI + f) * FO + n]) : 0u;
        }
        p[jj] = lo | (hi << 16);
    }
    unsigned int* op = (unsigned int*)&Bsw[tid * 8];
    op[0] = p[0]; op[1] = p[1]; op[2] = p[2]; op[3] = p[3];
}

// dweight [15][128][42] -> split-bf16 B-fragments dwB_{hi,lo}[nt(3)][kt(64)][lane(64)][8]
__global__ void build_dwB(const float* __restrict__ dw,
                          unsigned short* __restrict__ hi,
                          unsigned short* __restrict__ lo) {
    const int tid = blockIdx.x * 256 + threadIdx.x;   // 12288 total
    if (tid >= 3 * 64 * 64) return;
    const int lane = tid & 63;
    const int kt   = (tid >> 6) & 63;
    const int nt   = tid >> 12;
    const int o    = nt * 16 + (lane & 15);
    const int kbase = kt * 32 + (lane >> 4) * 8;
    #pragma unroll
    for (int j = 0; j < 8; j++) {
        const int kf = kbase + j;
        const int f = kf >> 4, k = kf & 15;
        float v = (k < KPN && o < OD) ? dw[(k * FI + f) * OD + o] : 0.f;
        unsigned short h = f2bf(v);
        hi[tid * 8 + j] = h;
        lo[tid * 8 + j] = f2bf(v - bf2f(h));
    }
}

// ------------------------- stage 1: offsets via split-bf16 MFMA -------------------------
// E=8 queries/block, 512 threads (8 waves). LDS ~73 KB -> 2 blocks/CU = 16 waves/CU.
// Phase B: wave w owns query w. Phase C: 6 waves = 3 nt x 2 K-halves, LDS reduce.
__global__ __launch_bounds__(512, 4)
void k1_offsets(const float* __restrict__ query, const float* __restrict__ support,
                const int* __restrict__ neighbors, const unsigned int* __restrict__ featpk,
                const float* __restrict__ kpoints,
                const unsigned short* __restrict__ dwB_hi,
                const unsigned short* __restrict__ dwB_lo,
                const float* __restrict__ bias, float* __restrict__ defkp)
{
    __shared__ unsigned short wfA_hi[8 * WFA_STRIDE];   // 32896 B
    __shared__ unsigned short wfA_lo[8 * WFA_STRIDE];   // 32896 B
    __shared__ float relx[256], rely[256], relz[256];   // 3072 B
    __shared__ int   nbr_s[256];                        // 1024 B
    __shared__ float kp_s[48];
    __shared__ f32x4 cred[3 * 64];                      // 3072 B (K-half partials)

    const int t = threadIdx.x;
    const int qbase = blockIdx.x * 8;
    if (t < 45) kp_s[t] = kpoints[t];
    if (t >= 45 && t < 48) kp_s[t] = 0.f;

    if (t < 256) {
        const int e = t >> 5, n = t & 31;
        const int q = qbase + e;
        const int idx = neighbors[q * NN + n];
        nbr_s[t] = idx;
        relx[t] = support[idx * 3 + 0] - query[q * 3 + 0];
        rely[t] = support[idx * 3 + 1] - query[q * 3 + 1];
        relz[t] = support[idx * 3 + 2] - query[q * 3 + 2];
    }
    __syncthreads();

    const int wave = t >> 6, lane = t & 63;
    const int quad = lane >> 4, low = lane & 15;

    // Phase B: wf0[ee][kf] = sum_n w0[ee][n][k] * feat[n][f]  (split-bf16, fp32 C)
    {
        const int ee = wave;                 // one query per wave
        const int kb = (low < KPN) ? low * 3 : 0;
        const float kx = kp_s[kb + 0], ky = kp_s[kb + 1], kz = kp_s[kb + 2];
        union { unsigned short u[8]; bf16x8 v; } ah, al;
        int rows[8];
        #pragma unroll
        for (int j = 0; j < 8; j++) {
            const int ni = ee * 32 + quad * 8 + j;
            rows[j] = nbr_s[ni];
            const float dx = relx[ni] - kx;
            const float dy = rely[ni] - ky;
            const float dz = relz[ni] - kz;
            const float d = sqrtf(dx * dx + dy * dy + dz * dz);
            float w = 1.0f - d * INV_EXT;
            w = (low < KPN && w > 0.f) ? w : 0.f;
            const unsigned short h = f2bf(w);
            ah.u[j] = h;
            al.u[j] = f2bf(w - bf2f(h));
        }
        #pragma unroll
        for (int ft = 0; ft < 8; ft++) {
            union { unsigned int u[4]; bf16x8 v; } bh, bl;
            #pragma unroll
            for (int jj = 0; jj < 4; jj++) {
                const unsigned int d0 = featpk[rows[2 * jj] * FI + ft * 16 + low];
                const unsigned int d1 = featpk[rows[2 * jj + 1] * FI + ft * 16 + low];
                bh.u[jj] = __builtin_amdgcn_perm(d1, d0, 0x05040100u);  // lo16s
                bl.u[jj] = __builtin_amdgcn_perm(d1, d0, 0x07060302u);  // hi16s
            }
            f32x4 acc = {0.f, 0.f, 0.f, 0.f};
            acc = __builtin_amdgcn_mfma_f32_16x16x32_bf16(al.v, bh.v, acc, 0, 0, 0);
            acc = __builtin_amdgcn_mfma_f32_16x16x32_bf16(ah.v, bl.v, acc, 0, 0, 0);
            acc = __builtin_amdgcn_mfma_f32_16x16x32_bf16(ah.v, bh.v, acc, 0, 0, 0);
            // C element (row k'=quad*4+r, col f=ft*16+low) -> kf = f*16+k'
            const int kfb = (ft * 16 + low) * 16 + quad * 4;
            const unsigned short h0 = f2bf(acc[0]), h1 = f2bf(acc[1]);
            const unsigned short h2 = f2bf(acc[2]), h3 = f2bf(acc[3]);
            unsigned int* ph = (unsigned int*)&wfA_hi[ee * WFA_STRIDE + kfb];
            ph[0] = (unsigned int)h0 | ((unsigned int)h1 << 16);
            ph[1] = (unsigned int)h2 | ((unsigned int)h3 << 16);
            unsigned int* pl = (unsigned int*)&wfA_lo[ee * WFA_STRIDE + kfb];
            pl[0] = (unsigned int)f2bf(acc[0] - bf2f(h0)) |
                    ((unsigned int)f2bf(acc[1] - bf2f(h1)) << 16);
            pl[1] = (unsigned int)f2bf(acc[2] - bf2f(h2)) |
                    ((unsigned int)f2bf(acc[3] - bf2f(h3)) << 16);
        }
    }
    __syncthreads();

    // Phase C: feat0[8e x 48o] = wfA[8e x 2048] * dwB[2048 x 48]  (split-bf16)
    // 6 waves: nt = wave>>1, half = wave&1 (32 kt each); reduce via LDS.
    f32x4 acc = {0.f, 0.f, 0.f, 0.f};
    const int nt = wave >> 1, half = wave & 1;
    if (wave < 6) {
        const bf16x8* Bh = (const bf16x8*)dwB_hi;
        const bf16x8* Bl = (const bf16x8*)dwB_lo;
        const int arow = (low & 7) * WFA_STRIDE;   // rows 8..15 duplicate 0..7
        const int kt0 = half * 32;
        for (int kt = kt0; kt < kt0 + 32; kt++) {
            bf16x8 a_h = *(const bf16x8*)&wfA_hi[arow + kt * 32 + quad * 8];
            bf16x8 a_l = *(const bf16x8*)&wfA_lo[arow + kt * 32 + quad * 8];
            bf16x8 b_h = Bh[(nt * KT2 + kt) * 64 + lane];
            bf16x8 b_l = Bl[(nt * KT2 + kt) * 64 + lane];
            acc = __builtin_amdgcn_mfma_f32_16x16x32_bf16(a_l, b_h, acc, 0, 0, 0);
            acc = __builtin_amdgcn_mfma_f32_16x16x32_bf16(a_h, b_l, acc, 0, 0, 0);
            acc = __builtin_amdgcn_mfma_f32_16x16x32_bf16(a_h, b_h, acc, 0, 0, 0);
        }
        if (half == 1) cred[nt * 64 + lane] = acc;
    } else if (wave == 6 && lane < 24) {
        defkp[(qbase + lane / 3) * 45 + (lane % 3)] = kp_s[lane % 3];
    }
    __syncthreads();

    if (wave < 6 && half == 0) {
        f32x4 o2 = cred[nt * 64 + lane];
        acc[0] += o2[0]; acc[1] += o2[1]; acc[2] += o2[2]; acc[3] += o2[3];
        const int o = nt * 16 + low;
        if (quad < 2 && o < OD) {
            const float bo = bias[o] + kp_s[3 + o];
            #pragma unroll
            for (int r = 0; r < 4; r++) {
                const int ee = quad * 4 + r;                 // C row = e
                defkp[(qbase + ee) * 45 + 3 + o] = bo + acc[r];
            }
        }
    }
}

// ------------------------- stage 2 (bf16 MFMA): deformable conv -------------------------
// E=16 queries, 512 threads. LDS ~77 KB -> 2 blocks/CU (16 waves).
__global__ __launch_bounds__(512, 4)
void k2_deform(const float* __restrict__ query, const float* __restrict__ support,
               const int* __restrict__ neighbors, const unsigned short* __restrict__ featbf,
               const unsigned short* __restrict__ Bsw, const float* __restrict__ defkp,
               float* __restrict__ out)
{
    __shared__ unsigned short wfA[16 * WFA_STRIDE];      // 65792 B
    __shared__ float relx[512], rely[512], relz[512];    // 6144 B
    __shared__ float dk_s[16 * 45];                      // 2880 B
    __shared__ int   nbr_s[512];                         // 2048 B

    const int t = threadIdx.x;
    const int qbase = blockIdx.x * 16;

    for (int i = t; i < 16 * 45; i += 512) dk_s[i] = defkp[qbase * 45 + i];

    const int e = t >> 5, n = t & 31;
    const int q = qbase + e;
    const int idx = neighbors[q * NN + n];
    nbr_s[t] = idx;
    relx[t] = support[idx * 3 + 0] - query[q * 3 + 0];
    rely[t] = support[idx * 3 + 1] - query[q * 3 + 1];
    relz[t] = support[idx * 3 + 2] - query[q * 3 + 2];
    __syncthreads();

    const int wave = t >> 6, lane = t & 63;
    const int quad = lane >> 4, low = lane & 15;

    // wf1 via MFMA; A-frag (w1^T) recomputed per lane from rel + def_kp
    {
        const int kb = (low < KPN) ? low * 3 : 0;
        for (int ei = 0; ei < 2; ei++) {
            const int ee = wave * 2 + ei;
            const float kx = dk_s[ee * 45 + kb + 0];
            const float ky = dk_s[ee * 45 + kb + 1];
            const float kz = dk_s[ee * 45 + kb + 2];
            union { unsigned short u[8]; bf16x8 v; } a;
            int rows[8];
            #pragma unroll
            for (int j = 0; j < 8; j++) {
                const int ni = ee * 32 + quad * 8 + j;
                rows[j] = nbr_s[ni];
                const float dx = relx[ni] - kx;
                const float dy = rely[ni] - ky;
                const float dz = relz[ni] - kz;
                const float d = sqrtf(dx * dx + dy * dy + dz * dz);
                float w = 1.0f - d * INV_EXT;
                w = (low < KPN && w > 0.f) ? w : 0.f;
                a.u[j] = f2bf(w);
            }
            #pragma unroll
            for (int ft = 0; ft < 8; ft++) {
                unsigned int p[4];
                #pragma unroll
                for (int j = 0; j < 4; j++) {
                    unsigned int lo2 = featbf[rows[2 * j] * FI + ft * 16 + low];
                    unsigned int hi2 = featbf[rows[2 * j + 1] * FI + ft * 16 + low];
                    p[j] = lo2 | (hi2 << 16);
                }
                bf16x8 b;
                {
                    union { unsigned int u[4]; bf16x8 v; } cv;
                    cv.u[0] = p[0]; cv.u[1] = p[1]; cv.u[2] = p[2]; cv.u[3] = p[3];
                    b = cv.v;
                }
                f32x4 acc = {0.f, 0.f, 0.f, 0.f};
                acc = __builtin_amdgcn_mfma_f32_16x16x32_bf16(a.v, b, acc, 0, 0, 0);
                const unsigned int w0 = (unsigned int)f2bf(acc[0]) | ((unsigned int)f2bf(acc[1]) << 16);
                const unsigned int w1 = (unsigned int)f2bf(acc[2]) | ((unsigned int)f2bf(acc[3]) << 16);
                unsigned short* wp = &wfA[ee * WFA_STRIDE + (ft * 16 + low) * 16 + quad * 4];
                ((unsigned int*)wp)[0] = w0;
                ((unsigned int*)wp)[1] = w1;
            }
        }
    }
    __syncthreads();

    // GEMM2: out[16 x 256] = wfA[16 x 2048] * Bsw[2048 x 256], rolling prefetch
    {
        const int nt0 = wave * 2, nt1 = nt0 + 1;
        f32x4 acc0 = {0.f, 0.f, 0.f, 0.f}, acc1 = {0.f, 0.f, 0.f, 0.f};
        const bf16x8* Bp = (const bf16x8*)Bsw;
        bf16x8 a_c  = *(const bf16x8*)&wfA[low * WFA_STRIDE + quad * 8];
        bf16x8 b0_c = Bp[(nt0 * KT2) * 64 + lane];
        bf16x8 b1_c = Bp[(nt1 * KT2) * 64 + lane];
        for (int kt = 0; kt < KT2 - 1; kt++) {
            bf16x8 a_n  = *(const bf16x8*)&wfA[low * WFA_STRIDE + (kt + 1) * 32 + quad * 8];
            bf16x8 b0_n = Bp[(nt0 * KT2 + kt + 1) * 64 + lane];
            bf16x8 b1_n = Bp[(nt1 * KT2 + kt + 1) * 64 + lane];
            acc0 = __builtin_amdgcn_mfma_f32_16x16x32_bf16(a_c, b0_c, acc0, 0, 0, 0);
            acc1 = __builtin_amdgcn_mfma_f32_16x16x32_bf16(a_c, b1_c, acc1, 0, 0, 0);
            a_c = a_n; b0_c = b0_n; b1_c = b1_n;
        }
        acc0 = __builtin_amdgcn_mfma_f32_16x16x32_bf16(a_c, b0_c, acc0, 0, 0, 0);
        acc1 = __builtin_amdgcn_mfma_f32_16x16x32_bf16(a_c, b1_c, acc1, 0, 0, 0);
        #pragma unroll
        for (int r = 0; r < 4; r++) {
            const int ee = quad * 4 + r;
            out[(qbase + ee) * FO + nt0 * 16 + low] = acc0[r];
            out[(qbase + ee) * FO + nt1 * 16 + low] = acc1[r];
        }
    }
}

// -------------------------------------------------------------------------
extern "C" void kernel_launch(void* const* d_in, const int* in_sizes, int n_in,
                              void* d_out, int out_size, void* d_ws, size_t ws_size,
                              hipStream_t stream) {
    const float* query     = (const float*)d_in[0];
    const float* support   = (const float*)d_in[1];
    const int*   neighbors = (const int*)  d_in[2];
    const float* features  = (const float*)d_in[3];
    const float* kpoints   = (const float*)d_in[4];
    const float* weight    = (const float*)d_in[5];
    const float* dweight   = (const float*)d_in[6];
    const float* bias      = (const float*)d_in[7];
    float*       out       = (float*)d_out;

    char* ws = (char*)d_ws;
    float*          defkp  = (float*)(ws + WS_DEFKP);
    unsigned short* featbf = (unsigned short*)(ws + WS_FEATBF);
    unsigned short* Bsw    = (unsigned short*)(ws + WS_BSW);
    unsigned short* dwBh   = (unsigned short*)(ws + WS_DWBH);
    unsigned short* dwBl   = (unsigned short*)(ws + WS_DWBL);
    unsigned int*   featpk = (unsigned int*)(ws + WS_FEATPK);

    prep_feat<<<(NQ * FI / 4 + 255) / 256, 256, 0, stream>>>(features, featbf, featpk);
    build_dwB<<<48, 256, 0, stream>>>(dweight, dwBh, dwBl);
    swz_B<<<256, 256, 0, stream>>>(weight, Bsw);

    k1_offsets<<<NQ / 8, 512, 0, stream>>>(query, support, neighbors, featpk,
                                           kpoints, dwBh, dwBl, bias, defkp);
    k2_deform<<<NQ / 16, 512, 0, stream>>>(query, support, neighbors, featbf,
                                           Bsw, defkp, out);
}